// Round 7
// baseline (4282.540 us; speedup 1.0000x reference)
//
#include <hip/hip_runtime.h>

// Attention B=2,H=16,S=2048,D=64 fp32; out = softmax(where(mask, clip(QK^T/8,1e-9,1e9), -1e9)) V
// d_out = [out | p_attn] fp32.
// K0: mask -> bitmask (stored in spare upper bytes of first 512 p-row slots)
// K1: fused esum + unnormalized PV + punorm(bf16, packed into p rows) + inv stash + out
// K2: streaming expand punorm*inv -> f32 p rows.

#define B_ 2
#define H_ 16
#define S_ 2048
#define D_ 64
#define BQ 64            // q rows per block
#define NQT (S_ / BQ)    // 32 q tiles per (b,h)
#define NCH (S_ / 64)    // 32 k-chunks of 64

typedef __attribute__((ext_vector_type(8))) short bf16x8;
typedef __attribute__((ext_vector_type(4))) float f32x4;
typedef unsigned long long u64;

__device__ inline short f2bf(float f) {
    unsigned u = __float_as_uint(f);
    u = (u + 0x7FFFu + ((u >> 16) & 1u)) >> 16;   // RNE
    return (short)u;
}

// bitmask word L (L = (b*2048+qrow)*32 + ch) lives at u64 index slot*1024+768+(L&255), slot=L>>8
__device__ __forceinline__ size_t bmIdx(size_t L) {
    return (L >> 8) * 1024 + 768 + (L & 255);
}

// ---- row-major [64][64] tile load (fp32 global -> 4 float4 regs), coalesced ----
__device__ __forceinline__ void loadRM(const float* __restrict__ src, int tid, float4* r) {
#pragma unroll
    for (int it = 0; it < 2; ++it) {
        const int g = it * 256 + tid;
        const float4* s4 = reinterpret_cast<const float4*>(src + (g >> 3) * 64 + (g & 7) * 8);
        r[it * 2]     = s4[0];
        r[it * 2 + 1] = s4[1];
    }
}
// regs -> bf16 LDS row-major, 16B-granule XOR swizzle
__device__ __forceinline__ void writeRM(short* dst, int tid, const float4* r) {
#pragma unroll
    for (int it = 0; it < 2; ++it) {
        const int g = it * 256 + tid;
        const int row = g >> 3, b = g & 7;
        const float4 a = r[it * 2], c = r[it * 2 + 1];
        bf16x8 v;
        v[0]=f2bf(a.x); v[1]=f2bf(a.y); v[2]=f2bf(a.z); v[3]=f2bf(a.w);
        v[4]=f2bf(c.x); v[5]=f2bf(c.y); v[6]=f2bf(c.z); v[7]=f2bf(c.w);
        *reinterpret_cast<bf16x8*>(&dst[row * 64 + ((b ^ (row & 7)) << 3)]) = v;
    }
}
// V tile: global row-major -> regs (coalesced: 64 lanes read 256B lines)
__device__ __forceinline__ void loadVc(const float* __restrict__ src, int tid, float* vr) {
    const int d = tid & 63, kq = tid >> 6;
#pragma unroll
    for (int i = 0; i < 16; ++i)
        vr[i] = src[(size_t)(kq * 16 + i) * 64 + d];
}
// regs -> d-major [64 d][64 k] bf16 LDS, XOR granule swizzle
__device__ __forceinline__ void writeVc(short* dst, int tid, const float* vr) {
    const int d = tid & 63, kq = tid >> 6;
#pragma unroll
    for (int h = 0; h < 2; ++h) {
        bf16x8 v;
#pragma unroll
        for (int i = 0; i < 8; ++i) v[i] = f2bf(vr[h * 8 + i]);
        *reinterpret_cast<bf16x8*>(&dst[d * 64 + (((2 * kq + h) ^ (d & 7)) << 3)]) = v;
    }
}

// ======================= K0: build bitmask =======================
__global__ __launch_bounds__(256, 8) void build_bitmask(const int* __restrict__ M,
                                                        float* __restrict__ P)
{
    u64* Pq = reinterpret_cast<u64*>(P);
    const unsigned total = (unsigned)B_ * S_ * S_;            // 8,388,608
    const unsigned stride = gridDim.x * 256;
    for (unsigned i = blockIdx.x * 256 + threadIdx.x; i < total; i += stride) {
        const bool mk = (M[i] != 0);
        const u64 bal = __ballot(mk);
        if ((threadIdx.x & 63) == 0) {
            const unsigned L = i >> 6;
            Pq[bmIdx((size_t)L)] = bal;
        }
    }
}

// ======================= K1: fused pass =======================
#define BODY(CH, CUR, BMC, BMN)                                                \
  {                                                                            \
    const int ch_ = (CH);                                                      \
    if (ch_ + 1 < NCH) {                                                       \
      _Pragma("unroll") for (int j = 0; j < 4; ++j)                            \
        BMN[j] = BMq[bmIdx(Lbase + (size_t)j * 32 + (ch_ + 1))];               \
    }                                                                          \
    __builtin_amdgcn_s_setprio(1);                                             \
    _Pragma("unroll") for (int kc = 0; kc < 4; ++kc) {                         \
      const int kr = kc*16 + c16;                                              \
      bf16x8 kf0 = *(const bf16x8*)&Ks[CUR][kr*64 + ((g16 ^ rsw) << 3)];       \
      bf16x8 kf1 = *(const bf16x8*)&Ks[CUR][kr*64 + (((4+g16) ^ rsw) << 3)];   \
      f32x4 acc = {0.f,0.f,0.f,0.f};                                           \
      acc = __builtin_amdgcn_mfma_f32_16x16x32_bf16(qf0, kf0, acc, 0,0,0);     \
      acc = __builtin_amdgcn_mfma_f32_16x16x32_bf16(qf1, kf1, acc, 0,0,0);     \
      _Pragma("unroll") for (int j = 0; j < 4; ++j) {                          \
        float s = acc[j] * 0.125f;                                             \
        s = fminf(fmaxf(s, 1e-9f), 1e9f);                                      \
        const float e = ((BMC[j] >> (kc*16 + c16)) & 1ULL) ? __expf(s) : 0.f;  \
        esum[j] += e;                                                          \
        const int row = g16*4 + j, cg = kc*16 + c16;                           \
        Ps[wv][row*64 + ((cg & 7) | (((cg >> 3) ^ (row & 7)) << 3))] = f2bf(e);\
      }                                                                        \
    }                                                                          \
    _Pragma("unroll") for (int ks = 0; ks < 2; ++ks) {                         \
      bf16x8 pa = *(const bf16x8*)&Ps[wv][c16*64 + (((ks*4+g16) ^ rsw) << 3)]; \
      _Pragma("unroll") for (int dt = 0; dt < 4; ++dt) {                       \
        const int vr_ = dt*16 + c16;                                           \
        bf16x8 vb = *(const bf16x8*)&Vs[CUR][vr_*64 + (((ks*4+g16) ^ (vr_ & 7)) << 3)]; \
        o[dt] = __builtin_amdgcn_mfma_f32_16x16x32_bf16(pa, vb, o[dt], 0,0,0); \
      }                                                                        \
    }                                                                          \
    __builtin_amdgcn_s_setprio(0);                                             \
    {                                                                          \
      const int pr = lane >> 2, seg = lane & 3;                                \
      bf16x8 w0 = *(const bf16x8*)&Ps[wv][pr*64 + (((seg*2)     ^ (pr & 7)) << 3)]; \
      bf16x8 w1 = *(const bf16x8*)&Ps[wv][pr*64 + (((seg*2 + 1) ^ (pr & 7)) << 3)]; \
      char* rb = (char*)(Pg + (size_t)(wv*16 + pr) * S_) + (size_t)ch_*128 + seg*32; \
      *(bf16x8*)(rb)      = w0;                                                \
      *(bf16x8*)(rb + 16) = w1;                                                \
    }                                                                          \
    if (ch_ + 1 < NCH) { writeRM(Ks[(CUR)^1], tid, kA); writeVc(Vs[(CUR)^1], tid, vA); } \
    if (ch_ + 2 < NCH) { loadRM(Kb + (size_t)(ch_+2)*4096, tid, kA);           \
                         loadVc(Vb + (size_t)(ch_+2)*4096, tid, vA); }         \
    __syncthreads();                                                           \
  }

__global__ __launch_bounds__(256, 3) void attn_pass1(
    const float* __restrict__ Q, const float* __restrict__ K,
    const float* __restrict__ V, float* __restrict__ Out, float* __restrict__ P)
{
    __shared__ short Ks[2][4096];     // 16 KB
    __shared__ short Vs[2][4096];     // 16 KB (d-major)
    __shared__ short Ps[4][1024];     // 8 KB; also Q staging in prologue

    const int tid  = threadIdx.x;
    const int lane = tid & 63;
    const int wv   = tid >> 6;
    const int g16  = lane >> 4;
    const int c16  = lane & 15;
    const int rsw  = c16 & 7;

    const int wid = (blockIdx.x & 7) * (gridDim.x >> 3) + (blockIdx.x >> 3);
    const int bh = wid >> 5;
    const int qt = wid & 31;
    const int qbase = qt * BQ;

    const float* Qb = Q + ((size_t)bh * S_ + qbase) * D_;
    const float* Kb = K + (size_t)bh * S_ * D_;
    const float* Vb = V + (size_t)bh * S_ * D_;
    float*       Pg = P + ((size_t)bh * S_ + qbase) * S_;
    float*       Og = Out + ((size_t)bh * S_ + qbase) * D_;
    const u64*   BMq = reinterpret_cast<const u64*>(P);

    const size_t Lbase = ((size_t)(bh >> 4) * 2048 + qbase + wv * 16 + g16 * 4) * 32;

    float4 kA[4]; float vA[16];
    {
        float4 qA[4];
        loadRM(Qb, tid, qA);
        loadRM(Kb, tid, kA);
        loadVc(Vb, tid, vA);
        writeRM(&Ps[0][0], tid, qA);
    }
    __syncthreads();
    const int qrow = wv * 16 + c16;
    const short* Qst = &Ps[0][0];
    const bf16x8 qf0 = *(const bf16x8*)&Qst[qrow*64 + ((g16 ^ rsw) << 3)];
    const bf16x8 qf1 = *(const bf16x8*)&Qst[qrow*64 + (((4+g16) ^ rsw) << 3)];
    writeRM(Ks[0], tid, kA);
    writeVc(Vs[0], tid, vA);
    loadRM(Kb + 4096, tid, kA);
    loadVc(Vb + 4096, tid, vA);

    u64 bm0[4], bm1[4];
#pragma unroll
    for (int j = 0; j < 4; ++j) bm0[j] = BMq[bmIdx(Lbase + (size_t)j * 32)];
    __syncthreads();

    float esum[4] = {0.f, 0.f, 0.f, 0.f};
    f32x4 o[4];
#pragma unroll
    for (int dt = 0; dt < 4; ++dt) o[dt] = f32x4{0.f, 0.f, 0.f, 0.f};

    for (int t = 0; t < NCH/2; ++t) {
        BODY(2*t,     0, bm0, bm1)
        BODY(2*t + 1, 1, bm1, bm0)
    }

    float inv[4];
#pragma unroll
    for (int j = 0; j < 4; ++j) {
        float v = esum[j];
        v += __shfl_xor(v, 1);
        v += __shfl_xor(v, 2);
        v += __shfl_xor(v, 4);
        v += __shfl_xor(v, 8);
        inv[j] = 1.0f / v;
    }
    if (c16 == 0) {
#pragma unroll
        for (int j = 0; j < 4; ++j)
            Pg[(size_t)(wv*16 + g16*4 + j) * S_ + 1024] = inv[j];   // stash for K2
    }
#pragma unroll
    for (int dt = 0; dt < 4; ++dt)
#pragma unroll
        for (int j = 0; j < 4; ++j)
            Og[(size_t)(wv*16 + g16*4 + j) * D_ + dt*16 + c16] = o[dt][j] * inv[j];
}

// ======================= K2: streaming expand =======================
__global__ __launch_bounds__(256, 8) void expand_p(float* __restrict__ P)
{
    const int tid = threadIdx.x, lane = tid & 63, wv = tid >> 6;
    const size_t row0 = (size_t)blockIdx.x * 16 + wv * 4;
#pragma unroll
    for (int i = 0; i < 4; ++i) {
        float* rowp = P + (row0 + i) * S_;
        const float iv = rowp[1024];                         // inv stash (broadcast)
        bf16x8 r[4];
#pragma unroll
        for (int t = 0; t < 4; ++t)
            r[t] = *reinterpret_cast<const bf16x8*>(
                (const char*)rowp + (size_t)t * 1024 + (size_t)lane * 16);
        asm volatile("s_waitcnt vmcnt(0)" ::: "memory");     // all reads serviced before any write
#pragma unroll
        for (int t = 0; t < 4; ++t) {
            float4* dst = reinterpret_cast<float4*>(rowp + (size_t)t * 512 + (size_t)lane * 8);
#pragma unroll
            for (int h = 0; h < 2; ++h) {
                float4 f;
                f.x = __uint_as_float(((unsigned)(unsigned short)r[t][h*4+0]) << 16) * iv;
                f.y = __uint_as_float(((unsigned)(unsigned short)r[t][h*4+1]) << 16) * iv;
                f.z = __uint_as_float(((unsigned)(unsigned short)r[t][h*4+2]) << 16) * iv;
                f.w = __uint_as_float(((unsigned)(unsigned short)r[t][h*4+3]) << 16) * iv;
                dst[h] = f;
            }
        }
    }
}

extern "C" void kernel_launch(void* const* d_in, const int* in_sizes, int n_in,
                              void* d_out, int out_size, void* d_ws, size_t ws_size,
                              hipStream_t stream) {
    const float* Q = (const float*)d_in[0];
    const float* K = (const float*)d_in[1];
    const float* V = (const float*)d_in[2];
    const int*   M = (const int*)d_in[3];

    float* Out = (float*)d_out;
    float* P   = (float*)d_out + (size_t)B_ * H_ * S_ * D_;

    hipLaunchKernelGGL(build_bitmask, dim3(8192), dim3(256), 0, stream, M, P);
    hipLaunchKernelGGL(attn_pass1, dim3(B_ * H_ * NQT), dim3(256), 0, stream, Q, K, V, Out, P);
    hipLaunchKernelGGL(expand_p, dim3(B_ * H_ * S_ / 16), dim3(256), 0, stream, P);
}

// Round 8
// 249.321 us; speedup vs baseline: 17.1768x; 17.1768x over previous
//
#include <hip/hip_runtime.h>

// Attention B=2,H=16,S=2048,D=64 fp32; out = softmax(where(mask, clip(QK^T/8,1e-9,1e9), -1e9)) V
// d_out = [out | p_attn] fp32.
// Single fused kernel: pass A = QK^T + exp + esum + unnormalized PV (mask read once,
// bits cached in LDS); pass B = recompute QK^T (K is L2-resident), p = exp*inv, stream p.

#define B_ 2
#define H_ 16
#define S_ 2048
#define D_ 64
#define BQ 64            // q rows per block
#define NQT (S_ / BQ)    // 32 q tiles per (b,h)
#define NCH (S_ / 64)    // 32 k-chunks of 64

typedef __attribute__((ext_vector_type(8))) short bf16x8;
typedef __attribute__((ext_vector_type(4))) float f32x4;

__device__ inline short f2bf(float f) {
    unsigned u = __float_as_uint(f);
    u = (u + 0x7FFFu + ((u >> 16) & 1u)) >> 16;   // RNE
    return (short)u;
}

// ---- row-major [64][64] tile load (fp32 global -> 4 float4 regs), coalesced ----
__device__ __forceinline__ void loadRM(const float* __restrict__ src, int tid, float4* r) {
#pragma unroll
    for (int it = 0; it < 2; ++it) {
        const int g = it * 256 + tid;
        const float4* s4 = reinterpret_cast<const float4*>(src + (g >> 3) * 64 + (g & 7) * 8);
        r[it * 2]     = s4[0];
        r[it * 2 + 1] = s4[1];
    }
}
// regs -> bf16 LDS row-major, 16B-granule XOR swizzle
__device__ __forceinline__ void writeRM(short* dst, int tid, const float4* r) {
#pragma unroll
    for (int it = 0; it < 2; ++it) {
        const int g = it * 256 + tid;
        const int row = g >> 3, b = g & 7;
        const float4 a = r[it * 2], c = r[it * 2 + 1];
        bf16x8 v;
        v[0]=f2bf(a.x); v[1]=f2bf(a.y); v[2]=f2bf(a.z); v[3]=f2bf(a.w);
        v[4]=f2bf(c.x); v[5]=f2bf(c.y); v[6]=f2bf(c.z); v[7]=f2bf(c.w);
        *reinterpret_cast<bf16x8*>(&dst[row * 64 + ((b ^ (row & 7)) << 3)]) = v;
    }
}
// V tile: global row-major -> regs (coalesced: 64 lanes read 256B lines)
__device__ __forceinline__ void loadVc(const float* __restrict__ src, int tid, float* vr) {
    const int d = tid & 63, kq = tid >> 6;
#pragma unroll
    for (int i = 0; i < 16; ++i)
        vr[i] = src[(size_t)(kq * 16 + i) * 64 + d];
}
// regs -> d-major [64 d][64 k] bf16 LDS, XOR granule swizzle
__device__ __forceinline__ void writeVc(short* dst, int tid, const float* vr) {
    const int d = tid & 63, kq = tid >> 6;
#pragma unroll
    for (int h = 0; h < 2; ++h) {
        bf16x8 v;
#pragma unroll
        for (int i = 0; i < 8; ++i) v[i] = f2bf(vr[h * 8 + i]);
        *reinterpret_cast<bf16x8*>(&dst[d * 64 + (((2 * kq + h) ^ (d & 7)) << 3)]) = v;
    }
}

// =============== pass A body: esum + unnormalized PV + mask-bit capture ===============
#define BODY_A(CH, CUR, MVC, MVN)                                              \
  {                                                                            \
    const int ch_ = (CH);                                                      \
    if (ch_ + 1 < NCH) {                                                       \
      _Pragma("unroll") for (int kc = 0; kc < 4; ++kc)                         \
      _Pragma("unroll") for (int j = 0; j < 4; ++j)                            \
        MVN[kc*4+j] = Mb[mrow0 + (size_t)j*S_ + (size_t)(ch_+1)*64 + kc*16 + c16]; \
    }                                                                          \
    __builtin_amdgcn_s_setprio(1);                                             \
    _Pragma("unroll") for (int kc = 0; kc < 4; ++kc) {                         \
      const int kr = kc*16 + c16;                                              \
      bf16x8 kf0 = *(const bf16x8*)&Ks[CUR][kr*64 + ((g16 ^ rsw) << 3)];       \
      bf16x8 kf1 = *(const bf16x8*)&Ks[CUR][kr*64 + (((4+g16) ^ rsw) << 3)];   \
      f32x4 acc = {0.f,0.f,0.f,0.f};                                           \
      acc = __builtin_amdgcn_mfma_f32_16x16x32_bf16(qf0, kf0, acc, 0,0,0);     \
      acc = __builtin_amdgcn_mfma_f32_16x16x32_bf16(qf1, kf1, acc, 0,0,0);     \
      _Pragma("unroll") for (int j = 0; j < 4; ++j) {                          \
        float s = acc[j] * 0.125f;                                             \
        s = fminf(fmaxf(s, 1e-9f), 1e9f);                                      \
        const float e = MVC[kc*4+j] ? __expf(s) : 0.f;                         \
        esum[j] += e;                                                          \
        const int row = g16*4 + j, cg = kc*16 + c16;                           \
        Ps[wv][row*64 + ((cg & 7) | (((cg >> 3) ^ (row & 7)) << 3))] = f2bf(e);\
      }                                                                        \
    }                                                                          \
    _Pragma("unroll") for (int ks = 0; ks < 2; ++ks) {                         \
      bf16x8 pa = *(const bf16x8*)&Ps[wv][c16*64 + (((ks*4+g16) ^ rsw) << 3)]; \
      _Pragma("unroll") for (int dt = 0; dt < 4; ++dt) {                       \
        const int vr_ = dt*16 + c16;                                           \
        bf16x8 vb = *(const bf16x8*)&Vs[CUR][vr_*64 + (((ks*4+g16) ^ (vr_ & 7)) << 3)]; \
        o[dt] = __builtin_amdgcn_mfma_f32_16x16x32_bf16(pa, vb, o[dt], 0,0,0); \
      }                                                                        \
    }                                                                          \
    __builtin_amdgcn_s_setprio(0);                                             \
    {                                                                          \
      unsigned wb = 0;                                                         \
      _Pragma("unroll") for (int i = 0; i < 16; ++i)                           \
        wb |= (MVC[i] != 0 ? 1u : 0u) << i;                                    \
      MBh[tid * 34 + ch_] = (unsigned short)wb;                                \
    }                                                                          \
    if (ch_ + 1 < NCH) { writeRM(Ks[(CUR)^1], tid, kA); writeVc(Vs[(CUR)^1], tid, vA); } \
    if (ch_ + 2 < NCH) { loadRM(Kb + (size_t)(ch_+2)*4096, tid, kA);           \
                         loadVc(Vb + (size_t)(ch_+2)*4096, tid, vA); }         \
    __syncthreads();                                                           \
  }

// =============== pass B body: recompute, normalize, stream p ===============
#define BODY_B(CH, CUR, MKW)                                                   \
  {                                                                            \
    const int ch_ = (CH);                                                      \
    const unsigned mw_ = (MKW);                                                \
    __builtin_amdgcn_s_setprio(1);                                             \
    _Pragma("unroll") for (int kc = 0; kc < 4; ++kc) {                         \
      const int kr = kc*16 + c16;                                              \
      bf16x8 kf0 = *(const bf16x8*)&Ks[CUR][kr*64 + ((g16 ^ rsw) << 3)];       \
      bf16x8 kf1 = *(const bf16x8*)&Ks[CUR][kr*64 + (((4+g16) ^ rsw) << 3)];   \
      f32x4 acc = {0.f,0.f,0.f,0.f};                                           \
      acc = __builtin_amdgcn_mfma_f32_16x16x32_bf16(qf0, kf0, acc, 0,0,0);     \
      acc = __builtin_amdgcn_mfma_f32_16x16x32_bf16(qf1, kf1, acc, 0,0,0);     \
      _Pragma("unroll") for (int j = 0; j < 4; ++j) {                          \
        float s = acc[j] * 0.125f;                                             \
        s = fminf(fmaxf(s, 1e-9f), 1e9f);                                      \
        const float p = ((mw_ >> (kc*4 + j)) & 1u) ? __expf(s) * inv[j] : 0.f; \
        Pg[(size_t)(wv*16 + g16*4 + j)*S_ + (size_t)ch_*64 + kc*16 + c16] = p; \
      }                                                                        \
    }                                                                          \
    __builtin_amdgcn_s_setprio(0);                                             \
    if (ch_ + 1 < NCH) writeRM(Ks[(CUR)^1], tid, kA);                          \
    if (ch_ + 2 < NCH) loadRM(Kb + (size_t)(ch_+2)*4096, tid, kA);             \
    __syncthreads();                                                           \
  }

__global__ __launch_bounds__(256, 2) void attn_fused(
    const float* __restrict__ Q, const float* __restrict__ K,
    const float* __restrict__ V, const int* __restrict__ M,
    float* __restrict__ Out, float* __restrict__ P)
{
    __shared__ short Ks[2][4096];            // 16 KB
    __shared__ short Vs[2][4096];            // 16 KB (d-major)
    __shared__ short Ps[4][1024];            // 8 KB; also Q staging in prologue
    __shared__ unsigned short MBh[256 * 34]; // 17 KB mask bits, padded stride (bank-safe)

    const int tid  = threadIdx.x;
    const int wv   = tid >> 6;
    const int lane = tid & 63;
    const int g16  = lane >> 4;
    const int c16  = lane & 15;
    const int rsw  = c16 & 7;

    // XCD-aware bijective swizzle (1024 % 8 == 0)
    const int wid = (blockIdx.x & 7) * (gridDim.x >> 3) + (blockIdx.x >> 3);
    const int bh = wid >> 5;
    const int qt = wid & 31;
    const int qbase = qt * BQ;

    const float* Qb = Q + ((size_t)bh * S_ + qbase) * D_;
    const float* Kb = K + (size_t)bh * S_ * D_;
    const float* Vb = V + (size_t)bh * S_ * D_;
    const int*   Mb = M + (size_t)(bh >> 4) * S_ * S_;
    float*       Pg = P + ((size_t)bh * S_ + qbase) * S_;
    float*       Og = Out + ((size_t)bh * S_ + qbase) * D_;

    float4 kA[4]; float vA[16];

    // ---- prologue: Q staged via Ps; K/V chunk 0 staged; chunk 1 in flight ----
    {
        float4 qA[4];
        loadRM(Qb, tid, qA);
        loadRM(Kb, tid, kA);
        loadVc(Vb, tid, vA);
        writeRM(&Ps[0][0], tid, qA);
    }
    __syncthreads();
    const int qrow = wv * 16 + c16;
    const short* Qst = &Ps[0][0];
    const bf16x8 qf0 = *(const bf16x8*)&Qst[qrow*64 + ((g16 ^ rsw) << 3)];
    const bf16x8 qf1 = *(const bf16x8*)&Qst[qrow*64 + (((4+g16) ^ rsw) << 3)];
    writeRM(Ks[0], tid, kA);
    writeVc(Vs[0], tid, vA);
    loadRM(Kb + 4096, tid, kA);
    loadVc(Vb + 4096, tid, vA);

    const size_t mrow0 = (size_t)(qbase + wv*16 + g16*4) * S_;
    int mv0[16], mv1[16];
#pragma unroll
    for (int kc = 0; kc < 4; ++kc)
#pragma unroll
        for (int j = 0; j < 4; ++j)
            mv0[kc*4+j] = Mb[mrow0 + (size_t)j*S_ + kc*16 + c16];
    __syncthreads();

    // =============== PASS A ===============
    float esum[4] = {0.f, 0.f, 0.f, 0.f};
    f32x4 o[4];
#pragma unroll
    for (int dt = 0; dt < 4; ++dt) o[dt] = f32x4{0.f, 0.f, 0.f, 0.f};

    for (int t = 0; t < NCH/2; ++t) {
        BODY_A(2*t,     0, mv0, mv1)
        BODY_A(2*t + 1, 1, mv1, mv0)
    }

    float inv[4];
#pragma unroll
    for (int j = 0; j < 4; ++j) {
        float v = esum[j];
        v += __shfl_xor(v, 1);
        v += __shfl_xor(v, 2);
        v += __shfl_xor(v, 4);
        v += __shfl_xor(v, 8);
        inv[j] = 1.0f / v;
    }
#pragma unroll
    for (int dt = 0; dt < 4; ++dt)
#pragma unroll
        for (int j = 0; j < 4; ++j)
            Og[(size_t)(wv*16 + g16*4 + j) * D_ + dt*16 + c16] = o[dt][j] * inv[j];

    // =============== PASS B prologue: restart K pipeline ===============
    loadRM(Kb, tid, kA);          // chunk 0
    writeRM(Ks[0], tid, kA);      // (all waves past pass-A final barrier)
    loadRM(Kb + 4096, tid, kA);   // chunk 1
    __syncthreads();

    for (int t = 0; t < NCH/2; ++t) {
        const unsigned w = *(const unsigned*)&MBh[tid * 34 + 2*t];
        BODY_B(2*t,     0, w & 0xffffu)
        BODY_B(2*t + 1, 1, w >> 16)
    }
}

extern "C" void kernel_launch(void* const* d_in, const int* in_sizes, int n_in,
                              void* d_out, int out_size, void* d_ws, size_t ws_size,
                              hipStream_t stream) {
    const float* Q = (const float*)d_in[0];
    const float* K = (const float*)d_in[1];
    const float* V = (const float*)d_in[2];
    const int*   M = (const int*)d_in[3];

    float* Out = (float*)d_out;
    float* P   = (float*)d_out + (size_t)B_ * H_ * S_ * D_;

    hipLaunchKernelGGL(attn_fused, dim3(B_ * H_ * NQT), dim3(256), 0, stream,
                       Q, K, V, M, Out, P);
}